// Round 12
// baseline (7677.250 us; speedup 1.0000x reference)
//
#include <hip/hip_runtime.h>

#define LOG2E 1.44269504088896340736f

__device__ __forceinline__ float lrelu(float z) { return fmaxf(z, 0.01f * z); }
__device__ __forceinline__ float sigf(float z) {
    float p = __builtin_amdgcn_exp2f(-LOG2E * z);
    return __builtin_amdgcn_rcpf(1.0f + p);
}

// Broadcast weight (i) from the lane-distributed register file (compile-time
// reg/lane after unroll): v_readlane_b32 -> SGPR -> scalar operand of v_fma.
#define WQ(i) __int_as_float(__builtin_amdgcn_readlane(__float_as_int(wreg[(i) >> 6]), (i) & 63))

// ============ Fused recurrence + output map, one thread per point ============
// R11 evidence: hpath at 1 wave/SIMD ran at ~4 cyc/VALU-instr (dep latency,
// VALUBusy 87%) and stores caused 10x write amplification (WRITE_SIZE 2.65GB
// for a 268MB output; 8B stores at 4KB lane stride). xpath re-read all of h.
// Fusing x=G(h) into the t-loop gives the scheduler independent work to fill
// the h-chain stall slots; buffering 8 steps of x in registers and flushing
// 64B/lane makes stores full-line; the h intermediate never touches HBM.
//
// Broadcast split (2424 weight floats), balanced VALU vs LDS pipe:
//   LDS   (780): Wh2 rows 0..17 (360) + Wx2 rows 29..49 (420)
//   wreg (1644): everything else, packed:
//     0..99    Wh1        | 100..149 bh1 | 150..789 Wh2 rows 18..49
//     790..809 bh2        | 810..849 Wh3 | 850..851 bh3
//     852..951 Wx1        | 952..1001 bx1
//     1002..1581 Wx2 rows 0..28 | 1582..1601 bx2
//     1602..1641 Wx3      | 1642..1643 bx3
__global__ void __launch_bounds__(256, 1)
fused_kernel(const float* __restrict__ w,
             const float* __restrict__ Wh1, const float* __restrict__ bh1,
             const float* __restrict__ Wh2, const float* __restrict__ bh2,
             const float* __restrict__ Wh3, const float* __restrict__ bh3,
             const float* __restrict__ Wx1, const float* __restrict__ bx1,
             const float* __restrict__ Wx2, const float* __restrict__ bx2,
             const float* __restrict__ Wx3, const float* __restrict__ bx3,
             float2* __restrict__ out, int B, int T)
{
    __shared__ float4 sW2h[90];    // Wh2 rows 0..17, row k at [5k..5k+4]
    __shared__ float4 sW2x[105];   // Wx2 rows 29..49, row (k-29) at [5(k-29)..]
    {
        float* a = (float*)sW2h;
        for (int i = threadIdx.x; i < 360; i += 256) a[i] = Wh2[i];
        float* b = (float*)sW2x;
        for (int i = threadIdx.x; i < 420; i += 256) b[i] = Wx2[580 + i];
    }

    const int lane = threadIdx.x & 63;
    float wreg[26];
#pragma unroll
    for (int r = 0; r < 26; ++r) {
        const int idx = r * 64 + lane;
        float v = 0.f;
        if      (idx < 100)  v = Wh1[idx];
        else if (idx < 150)  v = bh1[idx - 100];
        else if (idx < 790)  v = Wh2[360 + (idx - 150)];   // rows 18..49
        else if (idx < 810)  v = bh2[idx - 790];
        else if (idx < 850)  v = Wh3[idx - 810];
        else if (idx < 852)  v = bh3[idx - 850];
        else if (idx < 952)  v = Wx1[idx - 852];
        else if (idx < 1002) v = bx1[idx - 952];
        else if (idx < 1582) v = Wx2[idx - 1002];          // rows 0..28
        else if (idx < 1602) v = bx2[idx - 1582];
        else if (idx < 1642) v = Wx3[idx - 1602];
        else if (idx < 1644) v = bx3[idx - 1642];
        wreg[r] = v;
    }
    __syncthreads();

    const int bidx = blockIdx.x * blockDim.x + threadIdx.x;
    if (bidx >= B) return;   // B % 256 == 0: never taken

    float h0 = w[2 * bidx], h1 = w[2 * bidx + 1];
    float* __restrict__ orow = (float*)(out + (size_t)bidx * (size_t)T);

    float2 xb[8];   // 8-step output buffer -> one 64B full-line flush

    for (int t = 0; t < T; ++t) {
        // ======== h-path: h = lrelu3(h) ========
        float a1[50];
#pragma unroll
        for (int j = 0; j < 50; ++j)
            a1[j] = lrelu(fmaf(h0, WQ(j), fmaf(h1, WQ(50 + j), WQ(100 + j))));

        float acc[20];
#pragma unroll
        for (int c = 0; c < 20; ++c) acc[c] = WQ(790 + c);
#pragma unroll
        for (int k = 0; k < 18; ++k) {          // rows 0..17 via LDS
            const float ak = a1[k];
#pragma unroll
            for (int c = 0; c < 5; ++c) {
                const float4 v = sW2h[k * 5 + c];
                acc[4*c+0] = fmaf(ak, v.x, acc[4*c+0]);
                acc[4*c+1] = fmaf(ak, v.y, acc[4*c+1]);
                acc[4*c+2] = fmaf(ak, v.z, acc[4*c+2]);
                acc[4*c+3] = fmaf(ak, v.w, acc[4*c+3]);
            }
        }
#pragma unroll
        for (int k = 18; k < 50; ++k) {         // rows 18..49 via readlane
            const float ak = a1[k];
#pragma unroll
            for (int c = 0; c < 20; ++c)
                acc[c] = fmaf(ak, WQ(150 + (k - 18) * 20 + c), acc[c]);
        }

        float z0 = WQ(850), z1 = WQ(851);
#pragma unroll
        for (int k = 0; k < 20; ++k) {
            const float a2k = lrelu(acc[k]);
            z0 = fmaf(a2k, WQ(810 + 2 * k + 0), z0);
            z1 = fmaf(a2k, WQ(810 + 2 * k + 1), z1);
        }
        h0 = lrelu(z0); h1 = lrelu(z1);

        // ======== x-path: x = sig3(h), independent filler work ========
        float accx[20];
#pragma unroll
        for (int c = 0; c < 20; ++c) accx[c] = WQ(1582 + c);
#pragma unroll
        for (int k = 0; k < 50; ++k) {
            const float xk = sigf(fmaf(h0, WQ(852 + k), fmaf(h1, WQ(902 + k), WQ(952 + k))));
            if (k < 29) {                        // rows 0..28 via readlane
#pragma unroll
                for (int c = 0; c < 20; ++c)
                    accx[c] = fmaf(xk, WQ(1002 + k * 20 + c), accx[c]);
            } else {                             // rows 29..49 via LDS
#pragma unroll
                for (int c = 0; c < 5; ++c) {
                    const float4 v = sW2x[(k - 29) * 5 + c];
                    accx[4*c+0] = fmaf(xk, v.x, accx[4*c+0]);
                    accx[4*c+1] = fmaf(xk, v.y, accx[4*c+1]);
                    accx[4*c+2] = fmaf(xk, v.z, accx[4*c+2]);
                    accx[4*c+3] = fmaf(xk, v.w, accx[4*c+3]);
                }
            }
        }

        float zx0 = WQ(1642), zx1 = WQ(1643);
#pragma unroll
        for (int k = 0; k < 20; ++k) {
            const float xa = sigf(accx[k]);
            zx0 = fmaf(xa, WQ(1602 + 2 * k + 0), zx0);
            zx1 = fmaf(xa, WQ(1602 + 2 * k + 1), zx1);
        }
        xb[t & 7] = make_float2(sigf(zx0), sigf(zx1));

        // full-line flush: 8 steps x 8B = 64B per lane, 64B-aligned
        if ((t & 7) == 7) {
            const float4* s = (const float4*)xb;
            float4* d = (float4*)(orow + (t - 7) * 2);
            d[0] = s[0]; d[1] = s[1]; d[2] = s[2]; d[3] = s[3];
        }
    }
}

extern "C" void kernel_launch(void* const* d_in, const int* in_sizes, int n_in,
                              void* d_out, int out_size, void* d_ws, size_t ws_size,
                              hipStream_t stream)
{
    const float* w   = (const float*)d_in[0];
    const float* Wh1 = (const float*)d_in[1];
    const float* bh1 = (const float*)d_in[2];
    const float* Wh2 = (const float*)d_in[3];
    const float* bh2 = (const float*)d_in[4];
    const float* Wh3 = (const float*)d_in[5];
    const float* bh3 = (const float*)d_in[6];
    const float* Wx1 = (const float*)d_in[7];
    const float* bx1 = (const float*)d_in[8];
    const float* Wx2 = (const float*)d_in[9];
    const float* bx2 = (const float*)d_in[10];
    const float* Wx3 = (const float*)d_in[11];
    const float* bx3 = (const float*)d_in[12];

    const int B = in_sizes[0] / 2;        // 65536
    const int T = out_size / (B * 2);     // 512 (divisible by 8)

    fused_kernel<<<(B + 255) / 256, 256, 0, stream>>>(
        w, Wh1, bh1, Wh2, bh2, Wh3, bh3,
        Wx1, bx1, Wx2, bx2, Wx3, bx3,
        (float2*)d_out, B, T);
}

// Round 13
// 5959.978 us; speedup vs baseline: 1.2881x; 1.2881x over previous
//
#include <hip/hip_runtime.h>

#define LOG2E 1.44269504088896340736f

__device__ __forceinline__ float lrelu(float z) { return fmaxf(z, 0.01f * z); }
__device__ __forceinline__ float sigf(float z) {
    float p = __builtin_amdgcn_exp2f(-LOG2E * z);
    return __builtin_amdgcn_rcpf(1.0f + p);
}

// Broadcast weight (i) from the lane-distributed register file (compile-time
// reg/lane after unroll): v_readlane_b32 -> SGPR -> scalar operand of v_fma.
#define WQ(i) __int_as_float(__builtin_amdgcn_readlane(__float_as_int(wreg[(i) >> 6]), (i) & 63))

// ============ Fused recurrence + output map, one thread per point ============
// R12 lesson: the 8-step register output buffer xb[t&7] was runtime-indexed ->
// promote-alloca moved it to LDS (LDS_Block_Size 19968) and every access was a
// 32-way bank conflict (1.78e7 conflict cycles, VALUBusy 52%). R11 already
// proved direct per-step float2 stores are harmless (1.13 TB/s line traffic,
// 14% of HBM peak, 0 conflicts) -> store directly, no buffer.
//
// Broadcast split (2424 weight floats), balanced for the fused mix:
//   LDS   (740): Wh2 rows 0..17 (360) + Wx2 rows 31..49 (380)
//                -> 185 uniform ds_read_b128/wave/step, ~8.9K cyc/CU/round
//   wreg (1684): everything else -> VALU ~9.5K cyc/round incl. FMA+trans
// wreg packing:
//   0..99    Wh1 | 100..149 bh1 | 150..789 Wh2 rows 18..49
//   790..809 bh2 | 810..849 Wh3 | 850..851 bh3
//   852..951 Wx1 | 952..1001 bx1 | 1002..1621 Wx2 rows 0..30
//   1622..1641 bx2 | 1642..1681 Wx3 | 1682..1683 bx3
__global__ void __launch_bounds__(256, 1)
fused_kernel(const float* __restrict__ w,
             const float* __restrict__ Wh1, const float* __restrict__ bh1,
             const float* __restrict__ Wh2, const float* __restrict__ bh2,
             const float* __restrict__ Wh3, const float* __restrict__ bh3,
             const float* __restrict__ Wx1, const float* __restrict__ bx1,
             const float* __restrict__ Wx2, const float* __restrict__ bx2,
             const float* __restrict__ Wx3, const float* __restrict__ bx3,
             float2* __restrict__ out, int B, int T)
{
    __shared__ float4 sW2h[90];   // Wh2 rows 0..17, row k at [5k..5k+4]
    __shared__ float4 sW2x[95];   // Wx2 rows 31..49, row (k-31) at [5(k-31)..]
    {
        float* a = (float*)sW2h;
        for (int i = threadIdx.x; i < 360; i += 256) a[i] = Wh2[i];
        float* b = (float*)sW2x;
        for (int i = threadIdx.x; i < 380; i += 256) b[i] = Wx2[620 + i];
    }

    const int lane = threadIdx.x & 63;
    float wreg[27];
#pragma unroll
    for (int r = 0; r < 27; ++r) {
        const int idx = r * 64 + lane;
        float v = 0.f;
        if      (idx < 100)  v = Wh1[idx];
        else if (idx < 150)  v = bh1[idx - 100];
        else if (idx < 790)  v = Wh2[360 + (idx - 150)];   // rows 18..49
        else if (idx < 810)  v = bh2[idx - 790];
        else if (idx < 850)  v = Wh3[idx - 810];
        else if (idx < 852)  v = bh3[idx - 850];
        else if (idx < 952)  v = Wx1[idx - 852];
        else if (idx < 1002) v = bx1[idx - 952];
        else if (idx < 1622) v = Wx2[idx - 1002];          // rows 0..30
        else if (idx < 1642) v = bx2[idx - 1622];
        else if (idx < 1682) v = Wx3[idx - 1642];
        else if (idx < 1684) v = bx3[idx - 1682];
        wreg[r] = v;
    }
    __syncthreads();

    const int bidx = blockIdx.x * blockDim.x + threadIdx.x;
    if (bidx >= B) return;   // B % 256 == 0: never taken

    float h0 = w[2 * bidx], h1 = w[2 * bidx + 1];
    float2* __restrict__ orow = out + (size_t)bidx * (size_t)T;

    for (int t = 0; t < T; ++t) {
        // ======== h-path: h = lrelu3(h) ========
        float a1[50];
#pragma unroll
        for (int j = 0; j < 50; ++j)
            a1[j] = lrelu(fmaf(h0, WQ(j), fmaf(h1, WQ(50 + j), WQ(100 + j))));

        float acc[20];
#pragma unroll
        for (int c = 0; c < 20; ++c) acc[c] = WQ(790 + c);
#pragma unroll
        for (int k = 0; k < 18; ++k) {          // rows 0..17 via LDS
            const float ak = a1[k];
#pragma unroll
            for (int c = 0; c < 5; ++c) {
                const float4 v = sW2h[k * 5 + c];
                acc[4*c+0] = fmaf(ak, v.x, acc[4*c+0]);
                acc[4*c+1] = fmaf(ak, v.y, acc[4*c+1]);
                acc[4*c+2] = fmaf(ak, v.z, acc[4*c+2]);
                acc[4*c+3] = fmaf(ak, v.w, acc[4*c+3]);
            }
        }
#pragma unroll
        for (int k = 18; k < 50; ++k) {         // rows 18..49 via readlane
            const float ak = a1[k];
#pragma unroll
            for (int c = 0; c < 20; ++c)
                acc[c] = fmaf(ak, WQ(150 + (k - 18) * 20 + c), acc[c]);
        }

        float z0 = WQ(850), z1 = WQ(851);
#pragma unroll
        for (int k = 0; k < 20; ++k) {
            const float a2k = lrelu(acc[k]);
            z0 = fmaf(a2k, WQ(810 + 2 * k + 0), z0);
            z1 = fmaf(a2k, WQ(810 + 2 * k + 1), z1);
        }
        h0 = lrelu(z0); h1 = lrelu(z1);

        // ======== x-path: x = sig3(h) ========
        float accx[20];
#pragma unroll
        for (int c = 0; c < 20; ++c) accx[c] = WQ(1622 + c);
#pragma unroll
        for (int k = 0; k < 50; ++k) {
            const float xk = sigf(fmaf(h0, WQ(852 + k), fmaf(h1, WQ(902 + k), WQ(952 + k))));
            if (k < 31) {                        // rows 0..30 via readlane
#pragma unroll
                for (int c = 0; c < 20; ++c)
                    accx[c] = fmaf(xk, WQ(1002 + k * 20 + c), accx[c]);
            } else {                             // rows 31..49 via LDS
#pragma unroll
                for (int c = 0; c < 5; ++c) {
                    const float4 v = sW2x[(k - 31) * 5 + c];
                    accx[4*c+0] = fmaf(xk, v.x, accx[4*c+0]);
                    accx[4*c+1] = fmaf(xk, v.y, accx[4*c+1]);
                    accx[4*c+2] = fmaf(xk, v.z, accx[4*c+2]);
                    accx[4*c+3] = fmaf(xk, v.w, accx[4*c+3]);
                }
            }
        }

        float zx0 = WQ(1682), zx1 = WQ(1683);
#pragma unroll
        for (int k = 0; k < 20; ++k) {
            const float xa = sigf(accx[k]);
            zx0 = fmaf(xa, WQ(1642 + 2 * k + 0), zx0);
            zx1 = fmaf(xa, WQ(1642 + 2 * k + 1), zx1);
        }

        // direct per-step store (8B/lane; proven non-binding in R11)
        orow[t] = make_float2(sigf(zx0), sigf(zx1));
    }
}

extern "C" void kernel_launch(void* const* d_in, const int* in_sizes, int n_in,
                              void* d_out, int out_size, void* d_ws, size_t ws_size,
                              hipStream_t stream)
{
    const float* w   = (const float*)d_in[0];
    const float* Wh1 = (const float*)d_in[1];
    const float* bh1 = (const float*)d_in[2];
    const float* Wh2 = (const float*)d_in[3];
    const float* bh2 = (const float*)d_in[4];
    const float* Wh3 = (const float*)d_in[5];
    const float* bh3 = (const float*)d_in[6];
    const float* Wx1 = (const float*)d_in[7];
    const float* bx1 = (const float*)d_in[8];
    const float* Wx2 = (const float*)d_in[9];
    const float* bx2 = (const float*)d_in[10];
    const float* Wx3 = (const float*)d_in[11];
    const float* bx3 = (const float*)d_in[12];

    const int B = in_sizes[0] / 2;        // 65536
    const int T = out_size / (B * 2);     // 512

    fused_kernel<<<(B + 255) / 256, 256, 0, stream>>>(
        w, Wh1, bh1, Wh2, bh2, Wh3, bh3,
        Wx1, bx1, Wx2, bx2, Wx3, bx3,
        (float2*)d_out, B, T);
}

// Round 15
// 5437.669 us; speedup vs baseline: 1.4119x; 1.0961x over previous
//
#include <hip/hip_runtime.h>

#define LOG2E 1.44269504088896340736f

__device__ __forceinline__ float lrelu(float z) { return fmaxf(z, 0.01f * z); }
__device__ __forceinline__ float sigf(float z) {
    float p = __builtin_amdgcn_exp2f(-LOG2E * z);
    return __builtin_amdgcn_rcpf(1.0f + p);
}

// Broadcast weight (i) from the lane-distributed register file (compile-time
// reg/lane after unroll): v_readlane_b32 -> SGPR -> scalar operand of v_fma.
#define WQ(i) __int_as_float(__builtin_amdgcn_readlane(__float_as_int(wreg[(i) >> 6]), (i) & 63))

// ============ Producer-consumer: h-waves run F, x-waves run G ============
// R13 evidence: fusing F+G into one wave at 1 wave/SIMD ran at ~6.5 cyc/instr
// (latency-bound, VALUBusy 73%) and was SLOWER than the two-kernel split
// (5.96 vs 4.40 ms). R11 evidence: hpath alone at 1 wave/SIMD = 4.6 cyc/instr.
// Fix: wave specialization. Per block of 128 points: waves 0,1 compute the
// recurrence F only; waves 2,3 compute x=G(h) one step behind, reading h from
// a double-buffered LDS slot. 2048 waves total = 2 waves/SIMD -> dep-latency
// hiding; F and G run concurrently (time ~ max, not sum). One barrier per
// iteration, identical count on both paths (wave-granular producer-consumer).
// Both wave types use the SAME wreg packing layout (h-pack = Wh*, x-pack =
// Wx*), so F and G share the WQ index formulas:
//   0..99 W1 | 100..149 b1 | 150..1149 W2 | 1150..1169 b2
//   | 1170..1209 W3 | 1210..1211 b3
__global__ void __launch_bounds__(256, 2)
pc_kernel(const float* __restrict__ w,
          const float* __restrict__ Wh1, const float* __restrict__ bh1,
          const float* __restrict__ Wh2, const float* __restrict__ bh2,
          const float* __restrict__ Wh3, const float* __restrict__ bh3,
          const float* __restrict__ Wx1, const float* __restrict__ bx1,
          const float* __restrict__ Wx2, const float* __restrict__ bx2,
          const float* __restrict__ Wx3, const float* __restrict__ bx3,
          float2* __restrict__ out, int B, int T)
{
    __shared__ float2 hbuf[2][128];   // double-buffered h handoff (2 KB)

    const int wid  = threadIdx.x >> 6;        // 0..3
    const int lane = threadIdx.x & 63;
    const bool is_h = (wid < 2);
    const int lp = (wid & 1) * 64 + lane;     // local point 0..127
    const int p  = blockIdx.x * 128 + lp;     // global point (B % 128 == 0)

    const float* W1 = is_h ? Wh1 : Wx1;
    const float* B1 = is_h ? bh1 : bx1;
    const float* W2 = is_h ? Wh2 : Wx2;
    const float* B2 = is_h ? bh2 : bx2;
    const float* W3 = is_h ? Wh3 : Wx3;
    const float* B3 = is_h ? bh3 : bx3;

    float wreg[19];
#pragma unroll
    for (int r = 0; r < 19; ++r) {
        const int idx = r * 64 + lane;
        float v = 0.f;
        if      (idx < 100)  v = W1[idx];
        else if (idx < 150)  v = B1[idx - 100];
        else if (idx < 1150) v = W2[idx - 150];
        else if (idx < 1170) v = B2[idx - 1150];
        else if (idx < 1210) v = W3[idx - 1170];
        else if (idx < 1212) v = B3[idx - 1210];
        wreg[r] = v;
    }

    float h0 = 0.f, h1 = 0.f;
    if (is_h) { h0 = w[2 * p]; h1 = w[2 * p + 1]; }
    float2* __restrict__ orow = out + (size_t)p * (size_t)T;

    // T+1 iterations: h-waves do F at t<T; x-waves do G(t-1) at t>0.
    for (int t = 0; t <= T; ++t) {
        if (is_h) {
            if (t < T) {
                // ======== F: h = lrelu3(h)  (R10's proven body) ========
                float a1[50];
#pragma unroll
                for (int j = 0; j < 50; ++j)
                    a1[j] = lrelu(fmaf(h0, WQ(j), fmaf(h1, WQ(50 + j), WQ(100 + j))));

                float acc[20];
#pragma unroll
                for (int c = 0; c < 20; ++c) acc[c] = WQ(1150 + c);
#pragma unroll
                for (int k = 0; k < 50; ++k) {
                    const float ak = a1[k];
#pragma unroll
                    for (int c = 0; c < 20; ++c)
                        acc[c] = fmaf(ak, WQ(150 + k * 20 + c), acc[c]);
                }

                float z0 = WQ(1210), z1 = WQ(1211);
#pragma unroll
                for (int k = 0; k < 20; ++k) {
                    const float a2k = lrelu(acc[k]);
                    z0 = fmaf(a2k, WQ(1170 + 2 * k + 0), z0);
                    z1 = fmaf(a2k, WQ(1170 + 2 * k + 1), z1);
                }
                h0 = lrelu(z0); h1 = lrelu(z1);

                hbuf[t & 1][lp] = make_float2(h0, h1);   // publish h_t
            }
        } else {
            if (t > 0) {
                // ======== G: x_s = sig3(h_s), s = t-1 ========
                const int s = t - 1;
                const float2 hv = hbuf[s & 1][lp];

                float x1[50];
#pragma unroll
                for (int j = 0; j < 50; ++j)
                    x1[j] = sigf(fmaf(hv.x, WQ(j), fmaf(hv.y, WQ(50 + j), WQ(100 + j))));

                float accx[20];
#pragma unroll
                for (int c = 0; c < 20; ++c) accx[c] = WQ(1150 + c);
#pragma unroll
                for (int k = 0; k < 50; ++k) {
                    const float xk = x1[k];
#pragma unroll
                    for (int c = 0; c < 20; ++c)
                        accx[c] = fmaf(xk, WQ(150 + k * 20 + c), accx[c]);
                }

                float zx0 = WQ(1210), zx1 = WQ(1211);
#pragma unroll
                for (int k = 0; k < 20; ++k) {
                    const float xa = sigf(accx[k]);
                    zx0 = fmaf(xa, WQ(1170 + 2 * k + 0), zx0);
                    zx1 = fmaf(xa, WQ(1170 + 2 * k + 1), zx1);
                }

                orow[s] = make_float2(sigf(zx0), sigf(zx1));
            }
        }
        __syncthreads();   // orders hbuf[t&1] write -> read at t+1
    }
}

extern "C" void kernel_launch(void* const* d_in, const int* in_sizes, int n_in,
                              void* d_out, int out_size, void* d_ws, size_t ws_size,
                              hipStream_t stream)
{
    const float* w   = (const float*)d_in[0];
    const float* Wh1 = (const float*)d_in[1];
    const float* bh1 = (const float*)d_in[2];
    const float* Wh2 = (const float*)d_in[3];
    const float* bh2 = (const float*)d_in[4];
    const float* Wh3 = (const float*)d_in[5];
    const float* bh3 = (const float*)d_in[6];
    const float* Wx1 = (const float*)d_in[7];
    const float* bx1 = (const float*)d_in[8];
    const float* Wx2 = (const float*)d_in[9];
    const float* bx2 = (const float*)d_in[10];
    const float* Wx3 = (const float*)d_in[11];
    const float* bx3 = (const float*)d_in[12];

    const int B = in_sizes[0] / 2;        // 65536 (divisible by 128)
    const int T = out_size / (B * 2);     // 512

    // 128 points per block: waves 0,1 = F (producer), waves 2,3 = G (consumer)
    pc_kernel<<<B / 128, 256, 0, stream>>>(
        w, Wh1, bh1, Wh2, bh2, Wh3, bh3,
        Wx1, bx1, Wx2, bx2, Wx3, bx3,
        (float2*)d_out, B, T);
}